// Round 11
// baseline (128.137 us; speedup 1.0000x reference)
//
#include <hip/hip_runtime.h>

#define NPATH 60
#define KDIM  204
#define NIJ   324
#define NTIL  21       // 21 n-tiles of 16 (324 -> 336)
#define HID   64

typedef short bf16x8 __attribute__((ext_vector_type(8)));
typedef float f32x4  __attribute__((ext_vector_type(4)));

// One-time prepped operands in bf16 MFMA B-fragment order (module globals:
// graph-safe, rewritten by prep_kernel every call).
__device__ __align__(16) unsigned short g_w1s[4096];    // 2kc x 4nt x 64lane x 8
__device__ __align__(16) unsigned short g_w2s[4096];
__device__ __align__(16) unsigned short g_cgs[75264];   // 7kc x 21nt x 64lane x 8

// Compile-time p(k), y(k) tables -- replicate reference _filter_paths().
// Verified: 60 paths, K = 204. p(k) is NONDECREASING in k (paths enumerated in
// order) -- exploited by the split gather below: k<128 -> p<=38 (R dwords
// 0..19), k>=128 -> p>=38 (R dwords 19..29). Pad k>=204 uses p=59 (NOT 0) so
// half-1's compile-time indices stay inside its register window; the garbage
// product is multiplied by zero-padded cg -> exact 0.
struct PYTab {
    unsigned char pt[224];
    unsigned char yt[224];
    constexpr PYTab() : pt{}, yt{} {
        const int yoff[3] = {0, 1, 4};
        int k = 0, p = 0;
        for (int li = 0; li <= 2; li++)
            for (int lo = 0; lo <= 2; lo++) {
                int lmin = li - lo; if (lmin < 0) lmin = -lmin;
                int lmax = li + lo; if (lmax > 2) lmax = 2;
                for (int lf = lmin; lf <= lmax; lf++)
                    for (int m4 = 0; m4 < 4; m4++) {      // MUL*MUL copies
                        for (int m = 0; m < 2 * lf + 1; m++) {
                            pt[k] = (unsigned char)p;
                            yt[k] = (unsigned char)(yoff[lf] + m);
                            k++;
                        }
                        p++;
                    }
            }
        for (; k < 224; k++) { pt[k] = 59; yt[k] = 0; }
    }
};
constexpr PYTab PY{};

// Proven RNE f32->bf16 (round-0 verified). Do NOT replace with
// v_cvt_pk_bf16_f32 asm: round-1 showed that path zeroes the pipeline.
__device__ inline unsigned short f2bf(float f) {
    unsigned int u = __builtin_bit_cast(unsigned int, f);
    u += 0x7fffu + ((u >> 16) & 1u);     // RNE
    return (unsigned short)(u >> 16);
}
__device__ inline float bf2f(unsigned short h) {
    unsigned int u = ((unsigned int)h) << 16;
    return __builtin_bit_cast(float, u);
}

__global__ void prep_kernel(const float* __restrict__ W1, const float* __restrict__ W2,
                            const float* __restrict__ cg)
{
    int idx = blockIdx.x * 256 + threadIdx.x;
    if (idx < 4096) {                                       // W1 -> fragment order
        int e = idx & 7, ln = (idx >> 3) & 63, nt = (idx >> 9) & 3, kc = idx >> 11;
        int k = kc * 32 + (ln >> 4) * 8 + e;
        int n = nt * 16 + (ln & 15);
        g_w1s[idx] = f2bf(W1[k * HID + n]);
    } else if (idx < 8192) {                                // W2 (n>=60 zero)
        int j = idx - 4096;
        int e = j & 7, ln = (j >> 3) & 63, nt = (j >> 9) & 3, kc = j >> 11;
        int k = kc * 32 + (ln >> 4) * 8 + e;
        int n = nt * 16 + (ln & 15);
        g_w2s[j] = f2bf(n < NPATH ? W2[k * NPATH + n] : 0.0f);
    } else if (idx < 8192 + 75264) {                        // cg: source-order walk ->
        int j = idx - 8192;                                 // coalesced cg reads
        int k = j / 336;                                    // 224 k-slots (7kc x 32)
        int n = j % 336;                                    // 336 n-slots (21nt x 16)
        int kc = k >> 5, km = k & 31;
        int e  = km & 7, lh = km >> 3;
        int nt = n >> 4, lw = n & 15;
        int dst = ((kc * NTIL + nt) * 64 + (lh * 16 + lw)) * 8 + e;
        g_cgs[dst] = f2bf((k < KDIM && n < NIJ) ? cg[k * NIJ + n] : 0.0f);
    }
}

// Per-wave LDS slice -- wave-private, barrier-free (R6-proven discipline).
// Hw stride 88 u16 = 176 B (16B-aligned, 2-way banks = free).
// Rw stride 72 u16 = 144 B (16B-aligned for b128 row read-back; 2-way = free).
// Total 5120 B/wave x 4 waves x 8 blocks = exactly 160 KiB -> 8 blocks/CU.
struct __align__(16) WaveMem {
    unsigned short Hw[16][88];   // 2816 B  hidden activations (B -> C)
    unsigned short Rw[16][72];   // 2304 B  radial path weights (C -> D)
};                               // 5120 B per wave; x4 = 20480 B

union frag { bf16x8 v; unsigned int d[4]; };

// __launch_bounds__(256, 4): empirically (R2) caps the allocator at 64 VGPR.
// 64 VGPR is the 8-wave/SIMD occupancy boundary (m69) -> 32 waves/CU, double
// the 16 we get at 68-72 VGPR. The split Phase-D gather keeps peak live regs
// ~50 so the cap does NOT spill (R2 spilled because acc[6][4]=96 couldn't fit).
__global__ __launch_bounds__(256, 4) void fused_kernel(
    const float* __restrict__ r, const float* __restrict__ b1,
    const float* __restrict__ b2, float* __restrict__ out)
{
    __shared__ WaveMem wm[4];

    const int tid  = threadIdx.x;
    const int wv   = tid >> 6;
    const int lane = tid & 63;
    const int quad = lane >> 4;
    const int l16  = lane & 15;
    const int z0   = blockIdx.x * 64;
    WaveMem& W = wm[wv];

    // ---- Phase A (wave-local; ZERO block barriers in this kernel) ----
    const int zg = z0 + wv * 16 + l16;     // lane serves z-row l16 of the wave tile
    float x = r[zg * 3 + 0], y = r[zg * 3 + 1], zc = r[zg * 3 + 2];
    float rad = sqrtf(x * x + y * y + zc * zc);

    // Y in registers, computed redundantly by all 4 quads (no LDS).
    float yv[9];
    {
        float inv = 1.0f / (rad + 1e-12f);
        float nx = x * inv, ny = y * inv, nz = zc * inv;
        const float c0 = 0.28209479177387814f, c1 = 0.4886025119029199f;
        const float c2a = 1.0925484305920792f, c2b = 0.31539156525252005f, c2c = 0.5462742152960396f;
        yv[0] = c0;
        yv[1] = c1 * ny;
        yv[2] = c1 * nz;
        yv[3] = c1 * nx;
        yv[4] = c2a * nx * ny;
        yv[5] = c2a * ny * nz;
        yv[6] = c2b * (3.0f * nz * nz - 1.0f);
        yv[7] = c2a * nx * nz;
        yv[8] = c2c * (nx * nx - ny * ny);
    }

    // B-basis MFMA A-fragments in registers (A row = l16, col = quad*8+e).
    frag A0, A1;
    {
        const float step = 3.5f / 63.0f;
        const float NL2E = -5.770780163555852f;   // -4 * log2(e)
        #pragma unroll
        for (int ii = 0; ii < 4; ii++) {
            int i0 = quad * 8 + 2 * ii;
            float d0 = rad - (float)i0 * step;
            float d1 = rad - (float)(i0 + 1) * step;
            A0.d[ii] = (unsigned)f2bf(__builtin_amdgcn_exp2f(d0 * d0 * NL2E))
                     | ((unsigned)f2bf(__builtin_amdgcn_exp2f(d1 * d1 * NL2E)) << 16);
            int i2 = 32 + i0;
            float e0 = rad - (float)i2 * step;
            float e1 = rad - (float)(i2 + 1) * step;
            A1.d[ii] = (unsigned)f2bf(__builtin_amdgcn_exp2f(e0 * e0 * NL2E))
                     | ((unsigned)f2bf(__builtin_amdgcn_exp2f(e1 * e1 * NL2E)) << 16);
        }
    }

    // ---- Phase B (wave-local): H = relu(B @ W1 + b1) -> Hw ----
    #pragma unroll
    for (int nt = 0; nt < 4; nt++) {
        bf16x8 bb0 = *(const bf16x8*)&g_w1s[((0 * 4 + nt) * 64 + lane) * 8];
        bf16x8 bb1 = *(const bf16x8*)&g_w1s[((1 * 4 + nt) * 64 + lane) * 8];
        f32x4 acc = {0.f, 0.f, 0.f, 0.f};
        acc = __builtin_amdgcn_mfma_f32_16x16x32_bf16(A0.v, bb0, acc, 0, 0, 0);
        acc = __builtin_amdgcn_mfma_f32_16x16x32_bf16(A1.v, bb1, acc, 0, 0, 0);
        int h = nt * 16 + l16;
        float bias = b1[h];
        #pragma unroll
        for (int rr = 0; rr < 4; rr++) {
            float v = acc[rr] + bias;
            v = v > 0.0f ? v : 0.0f;
            W.Hw[quad * 4 + rr][h] = f2bf(v);     // H[z = quad*4+rr][h]
        }
    }
    // Wave-internal LDS visibility (fence discipline proven in rounds 5-6).
    asm volatile("s_waitcnt lgkmcnt(0)" ::: "memory");
    __builtin_amdgcn_sched_barrier(0);

    // ---- Phase C (wave-local): R = H @ W2 + b2 -> Rw ----
    {
        bf16x8 h0 = *(const bf16x8*)&W.Hw[l16][0 + quad * 8];
        bf16x8 h1 = *(const bf16x8*)&W.Hw[l16][32 + quad * 8];
        #pragma unroll
        for (int nt = 0; nt < 4; nt++) {
            bf16x8 bb0 = *(const bf16x8*)&g_w2s[((0 * 4 + nt) * 64 + lane) * 8];
            bf16x8 bb1 = *(const bf16x8*)&g_w2s[((1 * 4 + nt) * 64 + lane) * 8];
            f32x4 acc = {0.f, 0.f, 0.f, 0.f};
            acc = __builtin_amdgcn_mfma_f32_16x16x32_bf16(h0, bb0, acc, 0, 0, 0);
            acc = __builtin_amdgcn_mfma_f32_16x16x32_bf16(h1, bb1, acc, 0, 0, 0);
            int p = nt * 16 + l16;
            if (p < NPATH) {
                float bias = b2[p];
                #pragma unroll
                for (int rr = 0; rr < 4; rr++)
                    W.Rw[quad * 4 + rr][p] = f2bf(acc[rr] + bias);
            }
        }
    }
    asm volatile("s_waitcnt lgkmcnt(0)" ::: "memory");
    __builtin_amdgcn_sched_barrier(0);

    // ---- Phase D (registers, split halves to cap peak VGPR pressure) ----
    frag az[7];

    {   // Half 0: az[0..3] (k < 128) needs R dwords 0..19 only (p <= 38).
        union { uint4 q[5]; unsigned int u[20]; } R0;
        const uint4* rp = (const uint4*)&W.Rw[l16][0];
        #pragma unroll
        for (int j = 0; j < 5; j++) R0.q[j] = rp[j];
        asm volatile("s_waitcnt lgkmcnt(0)" ::: "memory");
        __builtin_amdgcn_sched_barrier(0);
        #pragma unroll
        for (int kc = 0; kc < 4; kc++) {
            #pragma unroll
            for (int ii = 0; ii < 4; ii++) {
                float a_[4], b_[4];
                #pragma unroll
                for (int qq = 0; qq < 4; qq++) {
                    const int kA = kc * 32 + qq * 8 + 2 * ii;
                    const int pA = PY.pt[kA],     yA = PY.yt[kA];
                    const int pB = PY.pt[kA + 1], yB = PY.yt[kA + 1];
                    float RA = bf2f((unsigned short)(R0.u[pA >> 1] >> (16 * (pA & 1))));
                    float RB = bf2f((unsigned short)(R0.u[pB >> 1] >> (16 * (pB & 1))));
                    a_[qq] = RA * yv[yA];
                    b_[qq] = RB * yv[yB];
                }
                float cA = (quad == 0) ? a_[0] : (quad == 1) ? a_[1] : (quad == 2) ? a_[2] : a_[3];
                float cB = (quad == 0) ? b_[0] : (quad == 1) ? b_[1] : (quad == 2) ? b_[2] : b_[3];
                az[kc].d[ii] = (unsigned)f2bf(cA) | ((unsigned)f2bf(cB) << 16);
            }
        }
    }
    {   // Half 1: az[4..6] (k >= 128) needs R dwords 16..31 only (p >= 38).
        union { uint4 q[4]; unsigned int u[16]; } R1;   // window base = dword 16
        const uint4* rp = (const uint4*)&W.Rw[l16][0];
        #pragma unroll
        for (int j = 0; j < 4; j++) R1.q[j] = rp[4 + j];
        asm volatile("s_waitcnt lgkmcnt(0)" ::: "memory");
        __builtin_amdgcn_sched_barrier(0);
        #pragma unroll
        for (int kc = 4; kc < 7; kc++) {
            #pragma unroll
            for (int ii = 0; ii < 4; ii++) {
                float a_[4], b_[4];
                #pragma unroll
                for (int qq = 0; qq < 4; qq++) {
                    const int kA = kc * 32 + qq * 8 + 2 * ii;
                    const int pA = PY.pt[kA],     yA = PY.yt[kA];
                    const int pB = PY.pt[kA + 1], yB = PY.yt[kA + 1];
                    float RA = bf2f((unsigned short)(R1.u[(pA >> 1) - 16] >> (16 * (pA & 1))));
                    float RB = bf2f((unsigned short)(R1.u[(pB >> 1) - 16] >> (16 * (pB & 1))));
                    a_[qq] = RA * yv[yA];
                    b_[qq] = RB * yv[yB];
                }
                float cA = (quad == 0) ? a_[0] : (quad == 1) ? a_[1] : (quad == 2) ? a_[2] : a_[3];
                float cB = (quad == 0) ? b_[0] : (quad == 1) ? b_[1] : (quad == 2) ? b_[2] : b_[3];
                az[kc].d[ii] = (unsigned)f2bf(cA) | ((unsigned)f2bf(cB) << 16);
            }
        }
    }

    // ---- Phase E (R6-proven, barrier-free): own 16 z-rows x ALL 21 n-tiles ----
    // out row = z0 + wv*16 + quad*4 + rr, col = nt*16 + l16 (proven mapping).
    const int obase = (z0 + wv * 16 + quad * 4) * NIJ + l16;
    #pragma unroll 3
    for (int nt = 0; nt < NTIL; nt++) {
        f32x4 acc = {0.f, 0.f, 0.f, 0.f};
        #pragma unroll
        for (int kc = 0; kc < 7; kc++) {
            bf16x8 bg = *(const bf16x8*)&g_cgs[((kc * NTIL + nt) * 64 + lane) * 8];
            acc = __builtin_amdgcn_mfma_f32_16x16x32_bf16(az[kc].v, bg, acc, 0, 0, 0);
        }
        int col = nt * 16 + l16;
        if (col < NIJ) {                     // last tile covers cols 320..335
            #pragma unroll
            for (int rr = 0; rr < 4; rr++)
                out[obase + rr * NIJ + nt * 16] = acc[rr];
        }
    }
}

extern "C" void kernel_launch(void* const* d_in, const int* in_sizes, int n_in,
                              void* d_out, int out_size, void* d_ws, size_t ws_size,
                              hipStream_t stream) {
    const float* r   = (const float*)d_in[0];
    const float* W1  = (const float*)d_in[1];
    const float* b1  = (const float*)d_in[2];
    const float* W2  = (const float*)d_in[3];
    const float* b2  = (const float*)d_in[4];
    const float* cg  = (const float*)d_in[5];
    float* out = (float*)d_out;

    const int Z = in_sizes[0] / 3;

    prep_kernel<<<327, 256, 0, stream>>>(W1, W2, cg);
    fused_kernel<<<Z / 64, 256, 0, stream>>>(r, b1, b2, out);
}

// Round 12
// 125.544 us; speedup vs baseline: 1.0207x; 1.0207x over previous
//
#include <hip/hip_runtime.h>

#define NPATH 60
#define KDIM  204
#define NIJ   324
#define NTIL  21       // 21 n-tiles of 16 (324 -> 336)
#define HID   64

typedef short bf16x8 __attribute__((ext_vector_type(8)));
typedef float f32x4  __attribute__((ext_vector_type(4)));

// One-time prepped operands in bf16 MFMA B-fragment order (module globals:
// graph-safe, rewritten by prep_kernel every call).
__device__ __align__(16) unsigned short g_w1s[4096];    // 2kc x 4nt x 64lane x 8
__device__ __align__(16) unsigned short g_w2s[4096];
__device__ __align__(16) unsigned short g_cgs[75264];   // 7kc x 21nt x 64lane x 8

// Compile-time p(k), y(k) tables -- replicate reference _filter_paths():
// paths: l_in 0..2 (outer), l_out 0..2, lf |l_in-l_out|..min(l_in+l_out,2),
// 4 (MUL^2) paths per lf; per path l: 2l+1 k's with y = y_off[l]+m.
// Verified: 60 paths, K = 204. Zero-pad k>=204 -> (p=0,y=0), harmless since
// cg is zero-padded there.
struct PYTab {
    unsigned char pt[224];
    unsigned char yt[224];
    constexpr PYTab() : pt{}, yt{} {
        const int yoff[3] = {0, 1, 4};
        int k = 0, p = 0;
        for (int li = 0; li <= 2; li++)
            for (int lo = 0; lo <= 2; lo++) {
                int lmin = li - lo; if (lmin < 0) lmin = -lmin;
                int lmax = li + lo; if (lmax > 2) lmax = 2;
                for (int lf = lmin; lf <= lmax; lf++)
                    for (int m4 = 0; m4 < 4; m4++) {      // MUL*MUL copies
                        for (int m = 0; m < 2 * lf + 1; m++) {
                            pt[k] = (unsigned char)p;
                            yt[k] = (unsigned char)(yoff[lf] + m);
                            k++;
                        }
                        p++;
                    }
            }
        for (; k < 224; k++) { pt[k] = 0; yt[k] = 0; }
    }
};
constexpr PYTab PY{};

// Proven RNE f32->bf16 (round-0 verified). Do NOT replace with
// v_cvt_pk_bf16_f32 asm: round-1 showed that path zeroes the pipeline.
__device__ inline unsigned short f2bf(float f) {
    unsigned int u = __builtin_bit_cast(unsigned int, f);
    u += 0x7fffu + ((u >> 16) & 1u);     // RNE
    return (unsigned short)(u >> 16);
}
__device__ inline float bf2f(unsigned short h) {
    unsigned int u = ((unsigned int)h) << 16;
    return __builtin_bit_cast(float, u);
}

__global__ void prep_kernel(const float* __restrict__ W1, const float* __restrict__ W2,
                            const float* __restrict__ cg)
{
    int idx = blockIdx.x * 256 + threadIdx.x;
    if (idx < 4096) {                                       // W1 -> fragment order
        int e = idx & 7, ln = (idx >> 3) & 63, nt = (idx >> 9) & 3, kc = idx >> 11;
        int k = kc * 32 + (ln >> 4) * 8 + e;
        int n = nt * 16 + (ln & 15);
        g_w1s[idx] = f2bf(W1[k * HID + n]);
    } else if (idx < 8192) {                                // W2 (n>=60 zero)
        int j = idx - 4096;
        int e = j & 7, ln = (j >> 3) & 63, nt = (j >> 9) & 3, kc = j >> 11;
        int k = kc * 32 + (ln >> 4) * 8 + e;
        int n = nt * 16 + (ln & 15);
        g_w2s[j] = f2bf(n < NPATH ? W2[k * NPATH + n] : 0.0f);
    } else if (idx < 8192 + 75264) {                        // cg: source-order walk ->
        int j = idx - 8192;                                 // coalesced cg reads
        int k = j / 336;                                    // 224 k-slots (7kc x 32)
        int n = j % 336;                                    // 336 n-slots (21nt x 16)
        int kc = k >> 5, km = k & 31;
        int e  = km & 7, lh = km >> 3;
        int nt = n >> 4, lw = n & 15;
        int dst = ((kc * NTIL + nt) * 64 + (lh * 16 + lw)) * 8 + e;
        g_cgs[dst] = f2bf((k < KDIM && n < NIJ) ? cg[k * NIJ + n] : 0.0f);
    }
}

// Per-wave LDS slice -- wave-private, barrier-free (R6-proven discipline).
// Hw stride 88 u16 = 176 B (16B-aligned, 2-way banks = free).
// Rw stride 72 u16 = 144 B (16B-aligned for b128 row read-back; rows l16 and
// l16+8 share a bank start = exact 2-way = free, m136). No Yw: Y lives in regs.
struct __align__(16) WaveMem {
    unsigned short Hw[16][88];   // 2816 B  hidden activations (B -> C)
    unsigned short Rw[16][72];   // 2304 B  radial path weights (C -> D)
};                               // 5120 B per wave; x4 = 20480 B

union frag { bf16x8 v; unsigned int d[4]; };

// Plain __launch_bounds__(256): round 2 proved forcing low VGPR spills the
// accumulators (+80 MB scratch traffic); round 11 proved (256,4) at 64 VGPR
// buys nothing (Phase E is L1/L2-streaming-bound, not TLP-bound).
__global__ __launch_bounds__(256) void fused_kernel(
    const float* __restrict__ r, const float* __restrict__ b1,
    const float* __restrict__ b2, float* __restrict__ out)
{
    __shared__ WaveMem wm[4];

    const int tid  = threadIdx.x;
    const int wv   = tid >> 6;
    const int lane = tid & 63;
    const int quad = lane >> 4;
    const int l16  = lane & 15;
    const int z0   = blockIdx.x * 64;
    WaveMem& W = wm[wv];

    // ---- Phase A (wave-local; ZERO barriers in this kernel) ----
    const int zg = z0 + wv * 16 + l16;     // lane serves z-row l16 of the wave tile
    float x = r[zg * 3 + 0], y = r[zg * 3 + 1], zc = r[zg * 3 + 2];
    float rad = sqrtf(x * x + y * y + zc * zc);

    // Y in registers, computed redundantly by all 4 quads (no LDS).
    float yv[9];
    {
        float inv = 1.0f / (rad + 1e-12f);
        float nx = x * inv, ny = y * inv, nz = zc * inv;
        const float c0 = 0.28209479177387814f, c1 = 0.4886025119029199f;
        const float c2a = 1.0925484305920792f, c2b = 0.31539156525252005f, c2c = 0.5462742152960396f;
        yv[0] = c0;
        yv[1] = c1 * ny;
        yv[2] = c1 * nz;
        yv[3] = c1 * nx;
        yv[4] = c2a * nx * ny;
        yv[5] = c2a * ny * nz;
        yv[6] = c2b * (3.0f * nz * nz - 1.0f);
        yv[7] = c2a * nx * nz;
        yv[8] = c2c * (nx * nx - ny * ny);
    }

    // B-basis MFMA A-fragments in registers (A row = l16, col = quad*8+e).
    frag A0, A1;
    {
        const float step = 3.5f / 63.0f;
        const float NL2E = -5.770780163555852f;   // -4 * log2(e)
        #pragma unroll
        for (int ii = 0; ii < 4; ii++) {
            int i0 = quad * 8 + 2 * ii;
            float d0 = rad - (float)i0 * step;
            float d1 = rad - (float)(i0 + 1) * step;
            A0.d[ii] = (unsigned)f2bf(__builtin_amdgcn_exp2f(d0 * d0 * NL2E))
                     | ((unsigned)f2bf(__builtin_amdgcn_exp2f(d1 * d1 * NL2E)) << 16);
            int i2 = 32 + i0;
            float e0 = rad - (float)i2 * step;
            float e1 = rad - (float)(i2 + 1) * step;
            A1.d[ii] = (unsigned)f2bf(__builtin_amdgcn_exp2f(e0 * e0 * NL2E))
                     | ((unsigned)f2bf(__builtin_amdgcn_exp2f(e1 * e1 * NL2E)) << 16);
        }
    }

    // ---- Phase B (wave-local): H = relu(B @ W1 + b1) -> Hw ----
    #pragma unroll
    for (int nt = 0; nt < 4; nt++) {
        bf16x8 bb0 = *(const bf16x8*)&g_w1s[((0 * 4 + nt) * 64 + lane) * 8];
        bf16x8 bb1 = *(const bf16x8*)&g_w1s[((1 * 4 + nt) * 64 + lane) * 8];
        f32x4 acc = {0.f, 0.f, 0.f, 0.f};
        acc = __builtin_amdgcn_mfma_f32_16x16x32_bf16(A0.v, bb0, acc, 0, 0, 0);
        acc = __builtin_amdgcn_mfma_f32_16x16x32_bf16(A1.v, bb1, acc, 0, 0, 0);
        int h = nt * 16 + l16;
        float bias = b1[h];
        #pragma unroll
        for (int rr = 0; rr < 4; rr++) {
            float v = acc[rr] + bias;
            v = v > 0.0f ? v : 0.0f;
            W.Hw[quad * 4 + rr][h] = f2bf(v);     // H[z = quad*4+rr][h]
        }
    }
    // Wave-internal LDS visibility (fence discipline proven in rounds 5-6).
    asm volatile("s_waitcnt lgkmcnt(0)" ::: "memory");
    __builtin_amdgcn_sched_barrier(0);

    // ---- Phase C (wave-local): R = H @ W2 + b2 -> Rw ----
    {
        bf16x8 h0 = *(const bf16x8*)&W.Hw[l16][0 + quad * 8];
        bf16x8 h1 = *(const bf16x8*)&W.Hw[l16][32 + quad * 8];
        #pragma unroll
        for (int nt = 0; nt < 4; nt++) {
            bf16x8 bb0 = *(const bf16x8*)&g_w2s[((0 * 4 + nt) * 64 + lane) * 8];
            bf16x8 bb1 = *(const bf16x8*)&g_w2s[((1 * 4 + nt) * 64 + lane) * 8];
            f32x4 acc = {0.f, 0.f, 0.f, 0.f};
            acc = __builtin_amdgcn_mfma_f32_16x16x32_bf16(h0, bb0, acc, 0, 0, 0);
            acc = __builtin_amdgcn_mfma_f32_16x16x32_bf16(h1, bb1, acc, 0, 0, 0);
            int p = nt * 16 + l16;
            if (p < NPATH) {
                float bias = b2[p];
                #pragma unroll
                for (int rr = 0; rr < 4; rr++)
                    W.Rw[quad * 4 + rr][p] = f2bf(acc[rr] + bias);
            }
        }
    }
    asm volatile("s_waitcnt lgkmcnt(0)" ::: "memory");
    __builtin_amdgcn_sched_barrier(0);

    // ---- Phase D (registers only): read back R row l16 as 8 x b128, then
    // gather with COMPILE-TIME p/y indices (no scattered LDS, no table loads).
    union { uint4 q[8]; unsigned int u[32]; } Rr;
    {
        const uint4* rp = (const uint4*)&W.Rw[l16][0];
        #pragma unroll
        for (int j = 0; j < 8; j++) Rr.q[j] = rp[j];
    }
    asm volatile("s_waitcnt lgkmcnt(0)" ::: "memory");
    __builtin_amdgcn_sched_barrier(0);

    frag az[7];
    #pragma unroll
    for (int kc = 0; kc < 7; kc++) {
        #pragma unroll
        for (int ii = 0; ii < 4; ii++) {
            float cA, cB;
            {
                // k index = kc*32 + quad*8 + 2*ii (+1). Extract per possible quad
                // at compile time, select by quad (wave-uniform per lane group).
                float a0_[4], b0_[4];
                #pragma unroll
                for (int qq = 0; qq < 4; qq++) {
                    const int kA = kc * 32 + qq * 8 + 2 * ii;
                    const int pA = PY.pt[kA],     yA = PY.yt[kA];
                    const int pB = PY.pt[kA + 1], yB = PY.yt[kA + 1];
                    float RA = bf2f((unsigned short)(Rr.u[pA >> 1] >> (16 * (pA & 1))));
                    float RB = bf2f((unsigned short)(Rr.u[pB >> 1] >> (16 * (pB & 1))));
                    a0_[qq] = RA * yv[yA];
                    b0_[qq] = RB * yv[yB];
                }
                cA = (quad == 0) ? a0_[0] : (quad == 1) ? a0_[1] : (quad == 2) ? a0_[2] : a0_[3];
                cB = (quad == 0) ? b0_[0] : (quad == 1) ? b0_[1] : (quad == 2) ? b0_[2] : b0_[3];
            }
            az[kc].d[ii] = (unsigned)f2bf(cA) | ((unsigned)f2bf(cB) << 16);
        }
    }

    // ---- Phase E (R6-proven, barrier-free): own 16 z-rows x ALL 21 n-tiles ----
    // out row = z0 + wv*16 + quad*4 + rr, col = nt*16 + l16 (proven mapping).
    const int obase = (z0 + wv * 16 + quad * 4) * NIJ + l16;
    #pragma unroll 3
    for (int nt = 0; nt < NTIL; nt++) {
        f32x4 acc = {0.f, 0.f, 0.f, 0.f};
        #pragma unroll
        for (int kc = 0; kc < 7; kc++) {
            bf16x8 bg = *(const bf16x8*)&g_cgs[((kc * NTIL + nt) * 64 + lane) * 8];
            acc = __builtin_amdgcn_mfma_f32_16x16x32_bf16(az[kc].v, bg, acc, 0, 0, 0);
        }
        int col = nt * 16 + l16;
        if (col < NIJ) {                     // last tile covers cols 320..335
            #pragma unroll
            for (int rr = 0; rr < 4; rr++)
                out[obase + rr * NIJ + nt * 16] = acc[rr];
        }
    }
}

extern "C" void kernel_launch(void* const* d_in, const int* in_sizes, int n_in,
                              void* d_out, int out_size, void* d_ws, size_t ws_size,
                              hipStream_t stream) {
    const float* r   = (const float*)d_in[0];
    const float* W1  = (const float*)d_in[1];
    const float* b1  = (const float*)d_in[2];
    const float* W2  = (const float*)d_in[3];
    const float* b2  = (const float*)d_in[4];
    const float* cg  = (const float*)d_in[5];
    float* out = (float*)d_out;

    const int Z = in_sizes[0] / 3;

    prep_kernel<<<327, 256, 0, stream>>>(W1, W2, cg);
    fused_kernel<<<Z / 64, 256, 0, stream>>>(r, b1, b2, out);
}